// Round 7
// baseline (413.206 us; speedup 1.0000x reference)
//
#include <hip/hip_runtime.h>

// RegressionWisard predict (centrality='mean')
//   input:  [B=4096, E=8192] int32 bits
//   map:    [E] permutation int32
//   counts: [N=512, 65536] int32 (values 0..3)
//   sums:   [N=512, 65536] float32
//   out:    [B] float32 = nan_to_num(sum(s where c>0) / sum(c where c>0))
//
// R7 (= R6 design, staging-count fix): gather->stream inversion.
//  - phaseA: per-thread 32-bit packing with i32x4 loads; acc zeroing folded.
//  - phaseB: QSPLIT=16 -> 20 KB LDS -> ~8 blocks/CU; slice = 4096 entries
//    -> staging is FOUR f32x4 + FOUR i32x4 per thread (R6 bug: only one,
//    leaving 3/4 of LDS uninitialized).

typedef float          f32x4 __attribute__((ext_vector_type(4)));
typedef int            i32x4 __attribute__((ext_vector_type(4)));
typedef unsigned short u16x8 __attribute__((ext_vector_type(8)));

constexpr int BATCH   = 4096;
constexpr int ENTRY   = 8192;
constexpr int TUP     = 16;
constexpr int NEUR    = ENTRY / TUP;      // 512
constexpr int SPB_A   = 4;                // samples per phase-A block
constexpr int QSPLIT  = 16;               // address-space slices per neuron
constexpr int QSIZE   = 65536 / QSPLIT;   // 4096 entries per slice

constexpr size_t ADDR_BYTES = (size_t)NEUR * BATCH * 2;       // 4 MB uint16
constexpr size_t ACC_OFF    = ADDR_BYTES;
constexpr size_t WS_NEED    = ADDR_BYTES + (size_t)BATCH * 8; // + 32 KB acc

// ---- Phase A: pack input bits, build addr[n][b]; also zero acc ----
__global__ __launch_bounds__(256) void phaseA_kernel(
    const int* __restrict__ input,
    const int* __restrict__ mapping,
    unsigned short* __restrict__ addr_out,
    unsigned long long* __restrict__ acc)
{
    __shared__ unsigned int packed[SPB_A][ENTRY / 32];   // 4 KB
    const int tid = threadIdx.x;
    const int b0  = blockIdx.x * SPB_A;

    // Fold accumulator zeroing into the first 16 blocks (4096 * 8 B).
    if (blockIdx.x < BATCH / 256) acc[blockIdx.x * 256 + tid] = 0ull;

    // Stage 1: thread t packs word t of each row from ints [32t, 32t+32).
    // 8 outstanding 16B nontemporal loads per row; no cross-lane ops.
    #pragma unroll
    for (int r = 0; r < SPB_A; ++r) {
        const i32x4* src = (const i32x4*)(input + (size_t)(b0 + r) * ENTRY) + tid * 8;
        i32x4 v[8];
        #pragma unroll
        for (int u = 0; u < 8; ++u) v[u] = __builtin_nontemporal_load(&src[u]);
        unsigned w = 0;
        #pragma unroll
        for (int u = 0; u < 8; ++u) {
            w |= ((unsigned)v[u].x & 1u) << (u * 4 + 0);
            w |= ((unsigned)v[u].y & 1u) << (u * 4 + 1);
            w |= ((unsigned)v[u].z & 1u) << (u * 4 + 2);
            w |= ((unsigned)v[u].w & 1u) << (u * 4 + 3);
        }
        packed[r][tid] = w;
    }
    __syncthreads();

    // Stage 2: 2 neurons/thread x 4 samples; t=0 is the MSB.
    #pragma unroll
    for (int k = 0; k < 2; ++k) {
        const int n = tid + k * 256;
        const int* map_n = mapping + n * TUP;
        int addr[SPB_A] = {0, 0, 0, 0};
        #pragma unroll
        for (int t = 0; t < TUP; ++t) {
            const int j = map_n[t];
            const unsigned w = j >> 5, sh = j & 31;
            #pragma unroll
            for (int s = 0; s < SPB_A; ++s)
                addr[s] = (addr[s] << 1) | ((packed[s][w] >> sh) & 1);
        }
        uint2 pk;
        pk.x = (unsigned)addr[0] | ((unsigned)addr[1] << 16);
        pk.y = (unsigned)addr[2] | ((unsigned)addr[3] << 16);
        *(uint2*)(addr_out + (size_t)n * BATCH + b0) = pk;   // 8B aligned
    }
}

// ---- Phase B: stream table slice through LDS, scatter packed atomics ----
// block = (neuron n, slice q). acc[b] += (round(s*2^24)<<20) + c for trained
// entries; Sum(c) <= 3*512 = 1536 < 2^20 so the fields never interact.
__global__ __launch_bounds__(256) void phaseB_kernel(
    const int*   __restrict__ counts,
    const float* __restrict__ sums,
    const unsigned short* __restrict__ addr,
    unsigned long long* __restrict__ acc)
{
    __shared__ float         s_tab[QSIZE];   // 16 KB
    __shared__ unsigned char c_tab[QSIZE];   //  4 KB
    const int tid = threadIdx.x;
    const int n   = blockIdx.x >> 4;
    const int q   = blockIdx.x & (QSPLIT - 1);
    const size_t base = ((size_t)n << 16) + (size_t)q * QSIZE;

    // Stage the slice: 4096 entries = 4 x (f32x4 + i32x4) per thread.
    const f32x4* s4 = (const f32x4*)(sums + base);
    const i32x4* c4 = (const i32x4*)(counts + base);
    f32x4 vs[4]; i32x4 vc[4];
    #pragma unroll
    for (int i = 0; i < 4; ++i) vs[i] = __builtin_nontemporal_load(&s4[tid + 256 * i]);
    #pragma unroll
    for (int i = 0; i < 4; ++i) vc[i] = __builtin_nontemporal_load(&c4[tid + 256 * i]);
    #pragma unroll
    for (int i = 0; i < 4; ++i) {
        ((f32x4*)s_tab)[tid + 256 * i] = vs[i];
        *(uchar4*)&c_tab[(tid + 256 * i) * 4] =
            make_uchar4((unsigned char)vc[i].x, (unsigned char)vc[i].y,
                        (unsigned char)vc[i].z, (unsigned char)vc[i].w);
    }
    __syncthreads();

    // Scan this neuron's 4096 addresses (16 per thread, two 16B loads;
    // row reused by all 16 q-blocks -> L2/L3-hot, keep temporal).
    const unsigned short* arow = addr + ((size_t)n << 12) + tid * 16;
    const u16x8 a0 = *(const u16x8*)(arow);
    const u16x8 a1 = *(const u16x8*)(arow + 8);
    #pragma unroll
    for (int j = 0; j < 16; ++j) {
        const int a = (j < 8) ? a0[j] : a1[j - 8];
        if ((a >> 12) == q) {
            const int local = a & (QSIZE - 1);
            const int c = c_tab[local];
            if (c) {
                const long long r =
                    (long long)__float2int_rn(s_tab[local] * 16777216.0f);
                atomicAdd(&acc[tid * 16 + j],
                          (unsigned long long)((r << 20) + (long long)c));
            }
        }
    }
}

// ---- Phase C: decode packed accumulator, divide ----
__global__ __launch_bounds__(256) void phaseC_kernel(
    const unsigned long long* __restrict__ acc, float* __restrict__ out)
{
    const int i = blockIdx.x * 256 + threadIdx.x;
    const long long v = (long long)acc[i];
    const int cnt = (int)(v & 0xFFFFF);
    const long long rq = v >> 20;   // arithmetic shift: signed resp sum
    out[i] = (cnt > 0)
        ? (float)(((double)rq * (1.0 / 16777216.0)) / (double)cnt)
        : 0.0f;                      // nan_to_num(0/0) == 0
}

// ---- Fallback (ws too small): direct gather ----
__global__ __launch_bounds__(256) void wisard_direct_kernel(
    const int* __restrict__ input, const int* __restrict__ mapping,
    const int* __restrict__ counts, const float* __restrict__ sums,
    float* __restrict__ out)
{
    __shared__ unsigned int packed[ENTRY / 32];
    __shared__ float s_resp[4];
    __shared__ int   s_cnt [4];
    const int tid = threadIdx.x, lane = tid & 63, wv = tid >> 6;
    const int* row = input + (size_t)blockIdx.x * ENTRY;
    for (int i = wv; i < ENTRY / 64; i += 4) {
        const unsigned long long m = __ballot(row[i * 64 + lane] & 1);
        if (lane == 0) {
            packed[i * 2] = (unsigned int)m;
            packed[i * 2 + 1] = (unsigned int)(m >> 32);
        }
    }
    __syncthreads();
    float resp = 0.0f; int cnt = 0;
    #pragma unroll
    for (int k = 0; k < 2; ++k) {
        const int n = tid + k * 256;
        const int* map_n = mapping + n * TUP;
        int a = 0;
        #pragma unroll
        for (int t = 0; t < TUP; ++t) {
            const int j = map_n[t];
            a = (a << 1) | ((packed[j >> 5] >> (j & 31)) & 1);
        }
        const int idx = (n << 16) | a;
        const int c = counts[idx];
        if (c > 0) { resp += sums[idx]; cnt += c; }
    }
    #pragma unroll
    for (int off = 32; off > 0; off >>= 1) {
        resp += __shfl_down(resp, off, 64);
        cnt  += __shfl_down(cnt,  off, 64);
    }
    if (lane == 0) { s_resp[wv] = resp; s_cnt[wv] = cnt; }
    __syncthreads();
    if (tid == 0) {
        float r = s_resp[0] + s_resp[1] + s_resp[2] + s_resp[3];
        int   c = s_cnt[0] + s_cnt[1] + s_cnt[2] + s_cnt[3];
        out[blockIdx.x] = (c > 0) ? (r / (float)c) : 0.0f;
    }
}

extern "C" void kernel_launch(void* const* d_in, const int* in_sizes, int n_in,
                              void* d_out, int out_size, void* d_ws, size_t ws_size,
                              hipStream_t stream) {
    (void)in_sizes; (void)n_in; (void)out_size;
    const int*   input   = (const int*)d_in[0];
    const int*   mapping = (const int*)d_in[1];
    const int*   counts  = (const int*)d_in[2];
    const float* sums    = (const float*)d_in[3];
    float*       out     = (float*)d_out;

    if (ws_size >= WS_NEED) {
        unsigned short*     addr_ws = (unsigned short*)d_ws;
        unsigned long long* acc     = (unsigned long long*)((char*)d_ws + ACC_OFF);
        phaseA_kernel<<<BATCH / SPB_A, 256, 0, stream>>>(input, mapping, addr_ws, acc);
        phaseB_kernel<<<NEUR * QSPLIT, 256, 0, stream>>>(counts, sums, addr_ws, acc);
        phaseC_kernel<<<BATCH / 256, 256, 0, stream>>>(acc, out);
    } else {
        wisard_direct_kernel<<<BATCH, 256, 0, stream>>>(input, mapping, counts, sums, out);
    }
}